// Round 6
// baseline (534.392 us; speedup 1.0000x reference)
//
#include <hip/hip_runtime.h>
#include <stdint.h>

// ExactTopKAttention: B=1, T=S=2048, H=16, E=64, topk=32, fp32.
//   - block = (head h, 16 t-rows), 512 threads = 8 waves, wave owns 2 rows
//   - QK^T GEMM fp32: K staged in LDS (512s x 16e swizzled), Q wave-uniform
//     loads; scores are a SEQUENTIAL fp32 FMA chain over e=0..63 (bit-
//     identical to BLAS/Eigen microkernels -> matches the np/jax reference's
//     fp32 rounding at the top-k boundary; final *0.125f commutes exactly)
//   - exact top-32 on those fp32 scores: adaptive 10-bit radix refinement
//     (overflow-proof, <=64 candidates guaranteed) -> 64-wide bitonic on
//     ((ord32<<32)|~idx)  (value desc, index asc = lax.top_k tie order)
//   - softmax over the 32 survivors (same fp32 scores), V gather, store.
//
// R6 change: __launch_bounds__(512) ONLY. R5's (512,4) made the allocator cap
// VGPRs at 64 (< the 64-float accumulator!) -> total spill: WRITE_SIZE 112MB,
// FETCH 92MB of scratch traffic. Honest need is ~110 VGPRs; uncapped, that
// lands <=128 -> 4 waves/SIMD, 16 waves/CU, zero scratch.

#define T_DIM 2048
#define S_DIM 2048
#define H_DIM 16
#define E_DIM 64
#define K_TOP 32
#define TT 16        // t rows per block
#define NWAVE 8      // waves per block
#define SCHUNK 512   // s rows per chunk
#define ESLICE 16    // e per LDS slice

// order-preserving float->uint map (monotone increasing)
__device__ __forceinline__ unsigned f2ord(float f) {
    unsigned b = __float_as_uint(f);
    return (b & 0x80000000u) ? ~b : (b | 0x80000000u);
}
__device__ __forceinline__ float ord2f(unsigned u) {
    unsigned b = (u & 0x80000000u) ? (u ^ 0x80000000u) : ~u;
    return __uint_as_float(b);
}
// histogram bank remap: bin b -> ((b&15)<<6)|(b>>4); lane L's descending
// 16-bin segment maps to consecutive banks (conflict-free scan).
__device__ __forceinline__ int hmap(int b) { return ((b & 15) << 6) | (b >> 4); }

__global__ __launch_bounds__(512)
void topk_attn_kernel(const float* __restrict__ Qg,
                      const float* __restrict__ Kg,
                      const float* __restrict__ Vg,
                      float* __restrict__ Out) {
    // 32 KB: K-tile during GEMM, 8 per-wave 1024-bin histograms afterwards.
    __shared__ __align__(16) float sK[SCHUNK * ESLICE];
    __shared__ unsigned candU[NWAVE][64];
    __shared__ int      candI[NWAVE][64];
    __shared__ unsigned wcnt[NWAVE];

    const int tid  = threadIdx.x;
    const int lane = tid & 63;
    const int wv   = tid >> 6;                 // wave 0..7
    const int bx   = blockIdx.x;
    const int h    = bx & (H_DIM - 1);         // consecutive bx -> same XCD per head
    const int tb   = bx >> 4;
    const int t0   = tb * TT + wv * 2;         // this wave's first t row

    unsigned* histw = ((unsigned*)sK) + wv * 1024;  // alias (post-GEMM only)

    // acc[jj][chunk][i]: score(t0+jj, s = chunk*512 + 64*i + lane), pre-scale
    float acc[2][4][8];
    #pragma unroll
    for (int a = 0; a < 2; a++)
        #pragma unroll
        for (int b = 0; b < 4; b++)
            #pragma unroll
            for (int c = 0; c < 8; c++) acc[a][b][c] = 0.f;

    const int swz = (lane >> 1) & 3;           // == ((s>>1)&3) for s = lane + 64*i

    #pragma unroll
    for (int ch = 0; ch < 4; ch++) {           // s chunks of 512
        for (int es = 0; es < 4; es++) {       // e slices of 16
            __syncthreads();
            // stage K[ch*512 .. +512)[es*16 .. +16) -> sK
            #pragma unroll
            for (int r = 0; r < 4; r++) {
                int p   = tid + 512 * r;       // float4 piece id, 2048 total
                int sl  = p >> 2;
                int col = p & 3;
                const float4 kv = *(const float4*)(Kg +
                    ((size_t)(ch * SCHUNK + sl) * H_DIM + h) * E_DIM
                    + es * ESLICE + col * 4);
                int slot = sl * 4 + ((col + ((sl >> 1) & 3)) & 3);  // XOR swizzle
                *(float4*)(sK + slot * 4) = kv;
            }
            __syncthreads();
            #pragma unroll
            for (int e4 = 0; e4 < 4; e4++) {
                float4 qf[2];
                #pragma unroll
                for (int jj = 0; jj < 2; jj++) {
                    int t = t0 + jj;
                    qf[jj] = *(const float4*)(Qg +
                        ((size_t)t * H_DIM + h) * E_DIM + es * ESLICE + e4 * 4);
                }
                #pragma unroll
                for (int i = 0; i < 8; i++) {
                    int sl   = lane + 64 * i;
                    int slot = sl * 4 + ((e4 + swz) & 3);
                    float4 kf = *(const float4*)(sK + slot * 4);
                    // e-sequential FMA chain (order matters for bit-match!)
                    #pragma unroll
                    for (int jj = 0; jj < 2; jj++) {
                        acc[jj][ch][i] = fmaf(qf[jj].x, kf.x, acc[jj][ch][i]);
                        acc[jj][ch][i] = fmaf(qf[jj].y, kf.y, acc[jj][ch][i]);
                        acc[jj][ch][i] = fmaf(qf[jj].z, kf.z, acc[jj][ch][i]);
                        acc[jj][ch][i] = fmaf(qf[jj].w, kf.w, acc[jj][ch][i]);
                    }
                }
            }
        }
    }

    __syncthreads();   // sK (K-tile) dead; hist may now alias it

    // ---- selection + softmax + output (wave-local; per-wave scratch) ----
    const float* Vb = Vg + (size_t)h * E_DIM;

    #pragma unroll
    for (int jj = 0; jj < 2; jj++) {
        // --- adaptive radix: find exact threshold with <=64 candidates ---
        unsigned prefix = 0, count_above = 0, cnt_eq = 0;
        bool done = false;
        #pragma unroll
        for (int lvl = 0; lvl < 3; lvl++) {
            if (!done) {                       // wave-uniform condition
                const int shift = 22 - 10 * lvl;
                #pragma unroll
                for (int z = 0; z < 16; z++) histw[z * 64 + lane] = 0u;
                #pragma unroll
                for (int ch = 0; ch < 4; ch++)
                    #pragma unroll
                    for (int i = 0; i < 8; i++) {
                        unsigned u = f2ord(acc[jj][ch][i] * 0.125f);
                        bool part = (lvl == 0) ||
                                    ((u >> (shift + 10)) == (prefix >> (shift + 10)));
                        if (part)
                            atomicAdd(&histw[hmap((int)((u >> shift) & 1023u))], 1u);
                    }
                const unsigned need = K_TOP - count_above;   // >=1, wave-uniform
                unsigned seg = 0;
                const int btop = 1023 - 16 * lane;           // descending segments
                #pragma unroll
                for (int k = 0; k < 16; k++) seg += histw[hmap(btop - k)];
                unsigned inc = seg;
                #pragma unroll
                for (int d = 1; d < 64; d <<= 1) {
                    unsigned y = __shfl_up(inc, d);
                    if (lane >= d) inc += y;
                }
                unsigned pre = inc - seg;                    // count above my segment
                bool cross = (pre < need) && (pre + seg >= need);
                int bl = 0; unsigned cg = 0, ce = 0;
                if (cross) {
                    unsigned c = pre;
                    #pragma unroll
                    for (int k = 0; k < 16; k++) {
                        unsigned hb = histw[hmap(btop - k)];
                        if (c < need && c + hb >= need) { bl = btop - k; cg = c; ce = hb; }
                        c += hb;
                    }
                }
                int src = __ffsll((unsigned long long)__ballot(cross)) - 1;
                bl = __shfl(bl, src);
                cg = __shfl(cg, src);
                ce = __shfl(ce, src);
                prefix |= ((unsigned)bl) << shift;
                count_above += cg;             // stays < 32
                cnt_eq = ce;
                done = (count_above + cnt_eq <= 60u) || (lvl == 2);
            }
        }

        // --- collect candidates with u >= prefix (exact; same bits as radix) ---
        if (lane == 0) wcnt[wv] = 0u;
        #pragma unroll
        for (int ch = 0; ch < 4; ch++)
            #pragma unroll
            for (int i = 0; i < 8; i++) {
                unsigned u = f2ord(acc[jj][ch][i] * 0.125f);
                if (u >= prefix) {
                    unsigned pos = atomicAdd(&wcnt[wv], 1u);
                    if (pos < 64u) {
                        candU[wv][pos] = u;
                        candI[wv][pos] = ch * SCHUNK + i * 64 + lane;
                    }
                }
            }
        unsigned n = wcnt[wv];                 // 32 <= n <= ~61 structurally
        if (n > 64u) n = 64u;

        // --- 64-wide bitonic, descending by (value, then lower index) ---
        unsigned long long key = 0ull;
        if ((unsigned)lane < n)
            key = (((unsigned long long)candU[wv][lane]) << 32)
                | (unsigned)(~candI[wv][lane]);
        #pragma unroll
        for (int k = 2; k <= 64; k <<= 1)
            #pragma unroll
            for (int j = k >> 1; j > 0; j >>= 1) {
                unsigned long long ok = __shfl_xor(key, j);
                bool takemax = ((lane & j) == 0) ^ ((lane & k) != 0);
                bool mineG   = key > ok;
                key = (takemax == mineG) ? key : ok;
            }

        // --- decode, softmax over lanes 0..31 (fp32 scores), V gather ---
        float val  = ord2f((unsigned)(key >> 32));
        int   sidx = (int)(~(unsigned)key);
        float m = __shfl(val, 0);              // lane 0 = max (n >= 32 always)
        float w = (lane < K_TOP) ? expf(val - m) : 0.f;
        float Z = w;
        #pragma unroll
        for (int d = 32; d > 0; d >>= 1) Z += __shfl_xor(Z, d);
        float p = w / Z;

        float o = 0.f;
        #pragma unroll
        for (int i2 = 0; i2 < K_TOP; i2++) {
            float pi = __shfl(p, i2);
            int   s2 = __shfl(sidx, i2);
            o = fmaf(pi, Vb[(size_t)s2 * (H_DIM * E_DIM) + lane], o);
        }
        int t = t0 + jj;
        Out[((size_t)t * H_DIM + h) * E_DIM + lane] = o;
    }
}

extern "C" void kernel_launch(void* const* d_in, const int* in_sizes, int n_in,
                              void* d_out, int out_size, void* d_ws, size_t ws_size,
                              hipStream_t stream) {
    const float* Q = (const float*)d_in[0];
    const float* K = (const float*)d_in[1];
    const float* V = (const float*)d_in[2];
    float* O = (float*)d_out;
    (void)in_sizes; (void)n_in; (void)out_size; (void)d_ws; (void)ws_size;
    dim3 grid((T_DIM / TT) * H_DIM);   // 2048 blocks
    dim3 block(512);
    topk_attn_kernel<<<grid, block, 0, stream>>>(Q, K, V, O);
}

// Round 7
// 489.397 us; speedup vs baseline: 1.0919x; 1.0919x over previous
//
#include <hip/hip_runtime.h>
#include <stdint.h>

// ExactTopKAttention: B=1, T=S=2048, H=16, E=64, topk=32, fp32.
//
// R7 restructure ("K^T streaming"): R6 counters proved the LDS-staged GEMM is
// LDS-pipe-bound (33.5 MB of ds_read per CU = ~164 us vs 55 us FMA floor),
// not VALU- or spill-bound. New dataflow:
//   kernel 1: transpose K per head -> KT[h][e][s] in d_ws (8 MB).
//   kernel 2: block = (h, 16 t-rows), 512 thr = 8 waves; wave owns a 256-wide
//     s-slice (lane = 4 consecutive s) and ALL 16 rows: acc[16] float4 = 64 VGPR.
//     Per e-pair: 2 coalesced float4 KT loads (L2-resident per head; bx&15=h
//     pins same-h blocks to one XCD) + Q via uniform-address s_loads.
//     128 FMAs / 2 VMEM loads, NO LDS, NO barriers in the GEMM.
//     Bit-exact: per (t,s) the chain is sequential fmaf over e=0..63, same as
//     BLAS/Eigen microkernels (matches np reference rounding; *0.125f at end
//     commutes exactly).
//   selection: 2 passes x 8 rows; scores -> LDS (64 KB), wave = row, 32
//     vals/lane stride-64 (conflict-free); then R3's proven adaptive radix
//     (overflow-proof <=64 cands) + 64-wide bitonic ((ord32<<32)|~idx, value
//     desc / index asc = lax.top_k tie order) + softmax + V gather.
//     Histograms alias the dead score buffer. LDS ~69.7 KB -> 2 blocks/CU.

#define T_DIM 2048
#define S_DIM 2048
#define H_DIM 16
#define E_DIM 64
#define K_TOP 32
#define TT 16        // t rows per block
#define NWAVE 8

// order-preserving float->uint map (monotone increasing)
__device__ __forceinline__ unsigned f2ord(float f) {
    unsigned b = __float_as_uint(f);
    return (b & 0x80000000u) ? ~b : (b | 0x80000000u);
}
__device__ __forceinline__ float ord2f(unsigned u) {
    unsigned b = (u & 0x80000000u) ? (u ^ 0x80000000u) : ~u;
    return __uint_as_float(b);
}
// histogram bank remap: bin b -> ((b&15)<<6)|(b>>4); lane L's descending
// 16-bin segment maps to consecutive banks (conflict-free scan).
__device__ __forceinline__ int hmap(int b) { return ((b & 15) << 6) | (b >> 4); }

// ---- kernel 1: K[s][h][e] -> KT[h][e][s] ----
__global__ __launch_bounds__(256)
void transpose_k(const float* __restrict__ Kg, float* __restrict__ KT) {
    __shared__ float tile[64][65];
    const int tid = threadIdx.x;
    const int h   = blockIdx.x & (H_DIM - 1);
    const int sb  = (blockIdx.x >> 4) * 64;
    #pragma unroll
    for (int sw = 0; sw < 4; sw++) {            // read 64s x 64e, coalesced on e
        int r = sw * 16 + (tid >> 4);
        int c = (tid & 15) * 4;
        float4 v = *(const float4*)(Kg + ((size_t)(sb + r) * H_DIM + h) * E_DIM + c);
        tile[r][c] = v.x; tile[r][c+1] = v.y; tile[r][c+2] = v.z; tile[r][c+3] = v.w;
    }
    __syncthreads();
    #pragma unroll
    for (int sw = 0; sw < 4; sw++) {            // write coalesced on s
        int e = sw * 16 + (tid >> 4);
        int j = (tid & 15) * 4;
        float4 v = { tile[j][e], tile[j+1][e], tile[j+2][e], tile[j+3][e] };
        *(float4*)(KT + ((size_t)h * E_DIM + e) * S_DIM + sb + j) = v;
    }
}

// ---- kernel 2: fused GEMM + exact top-32 + softmax + V ----
__global__ __launch_bounds__(512)
void topk_attn_kernel(const float* __restrict__ Qg,
                      const float* __restrict__ KT,
                      const float* __restrict__ Vg,
                      float* __restrict__ Out) {
    __shared__ __align__(16) float sS[8][S_DIM];   // 64 KB scores; hist aliases
    __shared__ unsigned candU[NWAVE][64];
    __shared__ int      candI[NWAVE][64];
    __shared__ unsigned wcnt[NWAVE];

    const int tid  = threadIdx.x;
    const int lane = tid & 63;
    const int wv   = tid >> 6;                 // wave 0..7
    const int bx   = blockIdx.x;
    const int h    = bx & (H_DIM - 1);         // same-h blocks -> same XCD
    const int tb   = bx >> 4;
    const int t0   = tb * TT;                  // block's first t row

    unsigned* histw = ((unsigned*)sS) + wv * 1024;   // alias (scores dead then)

    // ---- GEMM: acc[t] = float4 over this wave's 4 consecutive s ----
    float4 acc[16];
    #pragma unroll
    for (int t = 0; t < 16; t++) acc[t] = make_float4(0.f, 0.f, 0.f, 0.f);

    const int   sb  = wv * 256 + (lane << 2);  // first s of this lane
    const float* kp = KT + (size_t)h * E_DIM * S_DIM + sb;
    const float* Qb = Qg + ((size_t)t0 * H_DIM + h) * E_DIM;  // row stride 1024

    float4 k0 = *(const float4*)(kp);
    float4 k1 = *(const float4*)(kp + S_DIM);
    for (int e2 = 0; e2 < 32; e2++) {
        const int ep = (e2 + 1) & 31;          // wraps to 0 on last iter (harmless)
        float4 n0 = *(const float4*)(kp + (size_t)(2 * ep)     * S_DIM);
        float4 n1 = *(const float4*)(kp + (size_t)(2 * ep + 1) * S_DIM);
        #pragma unroll
        for (int t = 0; t < 16; t++) {
            // uniform address (blockIdx/loop-derived only) -> scalar load
            float2 qv = *(const float2*)(Qb + (size_t)t * (H_DIM * E_DIM) + 2 * e2);
            acc[t].x = fmaf(qv.x, k0.x, acc[t].x);
            acc[t].y = fmaf(qv.x, k0.y, acc[t].y);
            acc[t].z = fmaf(qv.x, k0.z, acc[t].z);
            acc[t].w = fmaf(qv.x, k0.w, acc[t].w);
            acc[t].x = fmaf(qv.y, k1.x, acc[t].x);
            acc[t].y = fmaf(qv.y, k1.y, acc[t].y);
            acc[t].z = fmaf(qv.y, k1.z, acc[t].z);
            acc[t].w = fmaf(qv.y, k1.w, acc[t].w);
        }
        k0 = n0; k1 = n1;
    }

    // ---- selection: 2 passes x 8 rows; wave wv selects local row wv ----
    const float* Vb = Vg + (size_t)h * E_DIM;

    for (int p = 0; p < 2; p++) {
        __syncthreads();                       // prior pass's hist use done
        #pragma unroll
        for (int r = 0; r < 8; r++)
            *(float4*)(&sS[r][sb]) = acc[p * 8 + r];
        __syncthreads();
        // wave wv reads full row wv: 32 vals/lane, s = i*64+lane (2-way=free)
        float vals[32];
        #pragma unroll
        for (int i = 0; i < 32; i++) vals[i] = sS[wv][i * 64 + lane];
        __syncthreads();                       // scores read -> hist may alias

        // --- adaptive radix: exact threshold with <=64 candidates ---
        unsigned prefix = 0, count_above = 0, cnt_eq = 0;
        bool done = false;
        #pragma unroll
        for (int lvl = 0; lvl < 3; lvl++) {
            if (!done) {                       // wave-uniform condition
                const int shift = 22 - 10 * lvl;
                #pragma unroll
                for (int z = 0; z < 16; z++) histw[z * 64 + lane] = 0u;
                #pragma unroll
                for (int i = 0; i < 32; i++) {
                    unsigned u = f2ord(vals[i] * 0.125f);
                    bool part = (lvl == 0) ||
                                ((u >> (shift + 10)) == (prefix >> (shift + 10)));
                    if (part)
                        atomicAdd(&histw[hmap((int)((u >> shift) & 1023u))], 1u);
                }
                const unsigned need = K_TOP - count_above;   // >=1, uniform
                unsigned seg = 0;
                const int btop = 1023 - 16 * lane;           // descending segs
                #pragma unroll
                for (int k = 0; k < 16; k++) seg += histw[hmap(btop - k)];
                unsigned inc = seg;
                #pragma unroll
                for (int d = 1; d < 64; d <<= 1) {
                    unsigned y = __shfl_up(inc, d);
                    if (lane >= d) inc += y;
                }
                unsigned pre = inc - seg;
                bool cross = (pre < need) && (pre + seg >= need);
                int bl = 0; unsigned cg = 0, ce = 0;
                if (cross) {
                    unsigned c = pre;
                    #pragma unroll
                    for (int k = 0; k < 16; k++) {
                        unsigned hb = histw[hmap(btop - k)];
                        if (c < need && c + hb >= need) { bl = btop - k; cg = c; ce = hb; }
                        c += hb;
                    }
                }
                int src = __ffsll((unsigned long long)__ballot(cross)) - 1;
                bl = __shfl(bl, src);
                cg = __shfl(cg, src);
                ce = __shfl(ce, src);
                prefix |= ((unsigned)bl) << shift;
                count_above += cg;             // stays < 32
                cnt_eq = ce;
                done = (count_above + cnt_eq <= 60u) || (lvl == 2);
            }
        }

        // --- collect candidates with u >= prefix (same bits as radix) ---
        if (lane == 0) wcnt[wv] = 0u;
        #pragma unroll
        for (int i = 0; i < 32; i++) {
            unsigned u = f2ord(vals[i] * 0.125f);
            if (u >= prefix) {
                unsigned pos = atomicAdd(&wcnt[wv], 1u);
                if (pos < 64u) {
                    candU[wv][pos] = u;
                    candI[wv][pos] = i * 64 + lane;
                }
            }
        }
        unsigned n = wcnt[wv];                 // 32 <= n <= ~61 structurally
        if (n > 64u) n = 64u;

        // --- 64-wide bitonic, descending by (value, then lower index) ---
        unsigned long long key = 0ull;
        if ((unsigned)lane < n)
            key = (((unsigned long long)candU[wv][lane]) << 32)
                | (unsigned)(~candI[wv][lane]);
        #pragma unroll
        for (int k = 2; k <= 64; k <<= 1)
            #pragma unroll
            for (int j = k >> 1; j > 0; j >>= 1) {
                unsigned long long ok = __shfl_xor(key, j);
                bool takemax = ((lane & j) == 0) ^ ((lane & k) != 0);
                bool mineG   = key > ok;
                key = (takemax == mineG) ? key : ok;
            }

        // --- decode, softmax over lanes 0..31, V gather, store ---
        float val  = ord2f((unsigned)(key >> 32));
        int   sidx = (int)(~(unsigned)key);
        float m = __shfl(val, 0);
        float w = (lane < K_TOP) ? expf(val - m) : 0.f;
        float Z = w;
        #pragma unroll
        for (int d = 32; d > 0; d >>= 1) Z += __shfl_xor(Z, d);
        float pr = w / Z;

        float o = 0.f;
        #pragma unroll
        for (int i2 = 0; i2 < K_TOP; i2++) {
            float pi = __shfl(pr, i2);
            int   s2 = __shfl(sidx, i2);
            o = fmaf(pi, Vb[(size_t)s2 * (H_DIM * E_DIM) + lane], o);
        }
        int t = t0 + p * 8 + wv;
        Out[((size_t)t * H_DIM + h) * E_DIM + lane] = o;
    }
}

extern "C" void kernel_launch(void* const* d_in, const int* in_sizes, int n_in,
                              void* d_out, int out_size, void* d_ws, size_t ws_size,
                              hipStream_t stream) {
    const float* Q = (const float*)d_in[0];
    const float* K = (const float*)d_in[1];
    const float* V = (const float*)d_in[2];
    float* O  = (float*)d_out;
    float* KT = (float*)d_ws;                  // 16*64*2048*4 = 8 MB
    (void)in_sizes; (void)n_in; (void)out_size; (void)ws_size;
    transpose_k<<<dim3(H_DIM * (S_DIM / 64)), dim3(256), 0, stream>>>(K, KT);
    topk_attn_kernel<<<dim3((T_DIM / TT) * H_DIM), dim3(512), 0, stream>>>(Q, KT, V, O);
}

// Round 8
// 276.141 us; speedup vs baseline: 1.9352x; 1.7723x over previous
//
#include <hip/hip_runtime.h>
#include <stdint.h>

// ExactTopKAttention: B=1, T=S=2048, H=16, E=64, topk=32, fp32.
//
// R8: R7's K^T-streaming GEMM was right (no LDS in GEMM), but the allocator
// chose 84 VGPRs vs ~112 live -> accumulator spill inside the K-loop
// (WRITE_SIZE 531 MB of scratch). Fix: make spill impossible.
//   - TT=8 rows/block (4096 blocks): acc[8] float4 = 32 VGPRs, peak live ~65.
//   - __launch_bounds__(512,2): empirically (R5) arg2 = min BLOCKS/CU, so 2
//     blocks * 8 waves = 16 waves/CU -> 128-reg cap (matches the LDS limit).
//   kernel 1: transpose K per head -> KT[h][e][s] in d_ws (8 MB).
//   kernel 2: block = (h, 8 t-rows); wave owns 256-wide s-slice (lane = 4
//     consecutive s) and all 8 rows. Per e-pair: 2 coalesced float4 KT loads
//     (L2-resident per head; bx&15=h pins same-h blocks to one XCD) + Q via
//     uniform-address scalar loads. No LDS/barriers in the GEMM.
//     Bit-exact: per (t,s) sequential fmaf chain over e=0..63 (matches the
//     np/BLAS reference rounding; *0.125f at the end commutes exactly).
//   selection (1 pass): scores -> LDS sS[8][2048]; wave = row, 32 vals/lane
//     stride-64 (conflict-free); adaptive 10-bit radix (overflow-proof,
//     <=64 cands) -> 64-wide bitonic on ((ord32<<32)|~idx) (value desc,
//     index asc = lax.top_k tie order) -> softmax -> V gather -> store.
//     Histograms alias the dead score buffer. LDS ~66 KB -> 2 blocks/CU.

#define T_DIM 2048
#define S_DIM 2048
#define H_DIM 16
#define E_DIM 64
#define K_TOP 32
#define TT 8         // t rows per block
#define NWAVE 8

// order-preserving float->uint map (monotone increasing)
__device__ __forceinline__ unsigned f2ord(float f) {
    unsigned b = __float_as_uint(f);
    return (b & 0x80000000u) ? ~b : (b | 0x80000000u);
}
__device__ __forceinline__ float ord2f(unsigned u) {
    unsigned b = (u & 0x80000000u) ? (u ^ 0x80000000u) : ~u;
    return __uint_as_float(b);
}
// histogram bank remap: bin b -> ((b&15)<<6)|(b>>4); lane L's descending
// 16-bin segment maps to consecutive banks (conflict-free scan).
__device__ __forceinline__ int hmap(int b) { return ((b & 15) << 6) | (b >> 4); }

// ---- kernel 1: K[s][h][e] -> KT[h][e][s] ----
__global__ __launch_bounds__(256)
void transpose_k(const float* __restrict__ Kg, float* __restrict__ KT) {
    __shared__ float tile[64][65];
    const int tid = threadIdx.x;
    const int h   = blockIdx.x & (H_DIM - 1);
    const int sb  = (blockIdx.x >> 4) * 64;
    #pragma unroll
    for (int sw = 0; sw < 4; sw++) {            // read 64s x 64e, coalesced on e
        int r = sw * 16 + (tid >> 4);
        int c = (tid & 15) * 4;
        float4 v = *(const float4*)(Kg + ((size_t)(sb + r) * H_DIM + h) * E_DIM + c);
        tile[r][c] = v.x; tile[r][c+1] = v.y; tile[r][c+2] = v.z; tile[r][c+3] = v.w;
    }
    __syncthreads();
    #pragma unroll
    for (int sw = 0; sw < 4; sw++) {            // write coalesced on s
        int e = sw * 16 + (tid >> 4);
        int j = (tid & 15) * 4;
        float4 v = { tile[j][e], tile[j+1][e], tile[j+2][e], tile[j+3][e] };
        *(float4*)(KT + ((size_t)h * E_DIM + e) * S_DIM + sb + j) = v;
    }
}

// ---- kernel 2: fused GEMM + exact top-32 + softmax + V ----
__global__ __launch_bounds__(512, 2)
void topk_attn_kernel(const float* __restrict__ Qg,
                      const float* __restrict__ KT,
                      const float* __restrict__ Vg,
                      float* __restrict__ Out) {
    __shared__ __align__(16) float sS[TT][S_DIM];   // 64 KB scores; hist aliases
    __shared__ unsigned candU[NWAVE][64];
    __shared__ int      candI[NWAVE][64];
    __shared__ unsigned wcnt[NWAVE];

    const int tid  = threadIdx.x;
    const int lane = tid & 63;
    const int wv   = tid >> 6;                 // wave 0..7
    const int bx   = blockIdx.x;
    const int h    = bx & (H_DIM - 1);         // same-h blocks -> same XCD
    const int tb   = bx >> 4;
    const int t0   = tb * TT;                  // block's first t row

    unsigned* histw = ((unsigned*)sS) + wv * 1024;   // alias (scores dead then)

    // ---- GEMM: acc[t] = float4 over this wave's 4 consecutive s ----
    float4 acc[TT];
    #pragma unroll
    for (int t = 0; t < TT; t++) acc[t] = make_float4(0.f, 0.f, 0.f, 0.f);

    const int   sb  = wv * 256 + (lane << 2);  // first s of this lane
    const float* kp = KT + (size_t)h * E_DIM * S_DIM + sb;
    const float* Qb = Qg + ((size_t)t0 * H_DIM + h) * E_DIM;  // row stride 1024

    float4 k0 = *(const float4*)(kp);
    float4 k1 = *(const float4*)(kp + S_DIM);
    for (int e2 = 0; e2 < 32; e2++) {
        const int ep = (e2 + 1) & 31;          // wraps to 0 on last iter (harmless)
        float4 n0 = *(const float4*)(kp + (size_t)(2 * ep)     * S_DIM);
        float4 n1 = *(const float4*)(kp + (size_t)(2 * ep + 1) * S_DIM);
        #pragma unroll
        for (int t = 0; t < TT; t++) {
            // uniform address (blockIdx/loop-derived only) -> scalar load
            float2 qv = *(const float2*)(Qb + (size_t)t * (H_DIM * E_DIM) + 2 * e2);
            acc[t].x = fmaf(qv.x, k0.x, acc[t].x);
            acc[t].y = fmaf(qv.x, k0.y, acc[t].y);
            acc[t].z = fmaf(qv.x, k0.z, acc[t].z);
            acc[t].w = fmaf(qv.x, k0.w, acc[t].w);
            acc[t].x = fmaf(qv.y, k1.x, acc[t].x);
            acc[t].y = fmaf(qv.y, k1.y, acc[t].y);
            acc[t].z = fmaf(qv.y, k1.z, acc[t].z);
            acc[t].w = fmaf(qv.y, k1.w, acc[t].w);
        }
        k0 = n0; k1 = n1;
    }

    // ---- selection: single pass, wave wv owns row wv ----
    const float* Vb = Vg + (size_t)h * E_DIM;

    #pragma unroll
    for (int r = 0; r < TT; r++)
        *(float4*)(&sS[r][sb]) = acc[r];
    __syncthreads();
    // wave wv reads full row wv: 32 vals/lane, s = i*64+lane (2-way = free)
    float vals[32];
    #pragma unroll
    for (int i = 0; i < 32; i++) vals[i] = sS[wv][i * 64 + lane];
    __syncthreads();                           // scores read -> hist may alias

    // --- adaptive radix: exact threshold with <=64 candidates ---
    unsigned prefix = 0, count_above = 0, cnt_eq = 0;
    bool done = false;
    #pragma unroll
    for (int lvl = 0; lvl < 3; lvl++) {
        if (!done) {                           // wave-uniform condition
            const int shift = 22 - 10 * lvl;
            #pragma unroll
            for (int z = 0; z < 16; z++) histw[z * 64 + lane] = 0u;
            #pragma unroll
            for (int i = 0; i < 32; i++) {
                unsigned u = f2ord(vals[i] * 0.125f);
                bool part = (lvl == 0) ||
                            ((u >> (shift + 10)) == (prefix >> (shift + 10)));
                if (part)
                    atomicAdd(&histw[hmap((int)((u >> shift) & 1023u))], 1u);
            }
            const unsigned need = K_TOP - count_above;   // >=1, uniform
            unsigned seg = 0;
            const int btop = 1023 - 16 * lane;           // descending segments
            #pragma unroll
            for (int k = 0; k < 16; k++) seg += histw[hmap(btop - k)];
            unsigned inc = seg;
            #pragma unroll
            for (int d = 1; d < 64; d <<= 1) {
                unsigned y = __shfl_up(inc, d);
                if (lane >= d) inc += y;
            }
            unsigned pre = inc - seg;
            bool cross = (pre < need) && (pre + seg >= need);
            int bl = 0; unsigned cg = 0, ce = 0;
            if (cross) {
                unsigned c = pre;
                #pragma unroll
                for (int k = 0; k < 16; k++) {
                    unsigned hb = histw[hmap(btop - k)];
                    if (c < need && c + hb >= need) { bl = btop - k; cg = c; ce = hb; }
                    c += hb;
                }
            }
            int src = __ffsll((unsigned long long)__ballot(cross)) - 1;
            bl = __shfl(bl, src);
            cg = __shfl(cg, src);
            ce = __shfl(ce, src);
            prefix |= ((unsigned)bl) << shift;
            count_above += cg;                 // stays < 32
            cnt_eq = ce;
            done = (count_above + cnt_eq <= 60u) || (lvl == 2);
        }
    }

    // --- collect candidates with u >= prefix (same bits as radix) ---
    if (lane == 0) wcnt[wv] = 0u;
    #pragma unroll
    for (int i = 0; i < 32; i++) {
        unsigned u = f2ord(vals[i] * 0.125f);
        if (u >= prefix) {
            unsigned pos = atomicAdd(&wcnt[wv], 1u);
            if (pos < 64u) {
                candU[wv][pos] = u;
                candI[wv][pos] = i * 64 + lane;
            }
        }
    }
    unsigned n = wcnt[wv];                     // 32 <= n <= ~61 structurally
    if (n > 64u) n = 64u;

    // --- 64-wide bitonic, descending by (value, then lower index) ---
    unsigned long long key = 0ull;
    if ((unsigned)lane < n)
        key = (((unsigned long long)candU[wv][lane]) << 32)
            | (unsigned)(~candI[wv][lane]);
    #pragma unroll
    for (int k = 2; k <= 64; k <<= 1)
        #pragma unroll
        for (int j = k >> 1; j > 0; j >>= 1) {
            unsigned long long ok = __shfl_xor(key, j);
            bool takemax = ((lane & j) == 0) ^ ((lane & k) != 0);
            bool mineG   = key > ok;
            key = (takemax == mineG) ? key : ok;
        }

    // --- decode, softmax over lanes 0..31, V gather, store ---
    float val  = ord2f((unsigned)(key >> 32));
    int   sidx = (int)(~(unsigned)key);
    float m = __shfl(val, 0);
    float w = (lane < K_TOP) ? expf(val - m) : 0.f;
    float Z = w;
    #pragma unroll
    for (int d = 32; d > 0; d >>= 1) Z += __shfl_xor(Z, d);
    float pr = w / Z;

    float o = 0.f;
    #pragma unroll
    for (int i2 = 0; i2 < K_TOP; i2++) {
        float pi = __shfl(pr, i2);
        int   s2 = __shfl(sidx, i2);
        o = fmaf(pi, Vb[(size_t)s2 * (H_DIM * E_DIM) + lane], o);
    }
    int t = t0 + wv;
    Out[((size_t)t * H_DIM + h) * E_DIM + lane] = o;
}

extern "C" void kernel_launch(void* const* d_in, const int* in_sizes, int n_in,
                              void* d_out, int out_size, void* d_ws, size_t ws_size,
                              hipStream_t stream) {
    const float* Q = (const float*)d_in[0];
    const float* K = (const float*)d_in[1];
    const float* V = (const float*)d_in[2];
    float* O  = (float*)d_out;
    float* KT = (float*)d_ws;                  // 16*64*2048*4 = 8 MB
    (void)in_sizes; (void)n_in; (void)out_size; (void)ws_size;
    transpose_k<<<dim3(H_DIM * (S_DIM / 64)), dim3(256), 0, stream>>>(K, KT);
    topk_attn_kernel<<<dim3((T_DIM / TT) * H_DIM), dim3(512), 0, stream>>>(Q, KT, V, O);
}

// Round 9
// 242.671 us; speedup vs baseline: 2.2021x; 1.1379x over previous
//
#include <hip/hip_runtime.h>
#include <stdint.h>

// ExactTopKAttention: B=1, T=S=2048, H=16, E=64, topk=32, fp32.
//
// R9: R8 counters attribute ~59 us to histogram same-address LDS atomic
// serialization (SQ_LDS_BANK_CONFLICT 3.6e7; scores concentrate into ~30 hot
// bins) plus ~40 us of radix VALU. Replace the whole adaptive radix with:
//   - one ballot/popcount counting pass at fixed threshold 16.0 (=2sigma of
//     the N(0,64) score distribution): count ~ Binom(2048,.0228) -> in
//     [32,64] for ~98% of rows; result is wave-uniform for free.
//   - rare fallback: exact bisection on ordered-uint bits (wave-uniform,
//     <=32 iters, lands on the exact 32nd-largest value; duplicate
//     pathology clamped at 64 as before).
// Selection sorts on PRE-scale ordered bits (x0.125 is an exact monotone
// pow2 map, applied at decode -> bit-identical softmax vs R8).
//
// Carried from R8 (proven):
//   kernel 1: transpose K per head -> KT[h][e][s] in d_ws (8 MB).
//   kernel 2: block = (h, 8 t-rows), 512 thr = 8 waves; wave owns a 256-wide
//     s-slice of all 8 rows; acc[8] float4 = 32 VGPRs (no spill; lb (512,2)).
//     Per e-pair: 2 coalesced float4 KT loads (L2-resident per head, bx&15=h
//     pins same-h blocks to one XCD) + Q uniform scalar loads. Bit-exact
//     sequential fmaf chain over e=0..63 per (t,s) (matches np/BLAS rounding).
//   selection: scores -> LDS sS[8][2048] (conflict-free), wave = row,
//     32 vals/lane stride-64; collect >= thr via tiny per-wave atomic append;
//     64-wide bitonic on ((ord32<<32)|~idx) (value desc, index asc =
//     lax.top_k tie order); softmax; V gather; store.

#define T_DIM 2048
#define S_DIM 2048
#define H_DIM 16
#define E_DIM 64
#define K_TOP 32
#define TT 8         // t rows per block
#define NWAVE 8

// order-preserving float->uint map (monotone increasing)
__device__ __forceinline__ unsigned f2ord(float f) {
    unsigned b = __float_as_uint(f);
    return (b & 0x80000000u) ? ~b : (b | 0x80000000u);
}
__device__ __forceinline__ float ord2f(unsigned u) {
    unsigned b = (u & 0x80000000u) ? (u ^ 0x80000000u) : ~u;
    return __uint_as_float(b);
}

// ---- kernel 1: K[s][h][e] -> KT[h][e][s] ----
__global__ __launch_bounds__(256)
void transpose_k(const float* __restrict__ Kg, float* __restrict__ KT) {
    __shared__ float tile[64][65];
    const int tid = threadIdx.x;
    const int h   = blockIdx.x & (H_DIM - 1);
    const int sb  = (blockIdx.x >> 4) * 64;
    #pragma unroll
    for (int sw = 0; sw < 4; sw++) {            // read 64s x 64e, coalesced on e
        int r = sw * 16 + (tid >> 4);
        int c = (tid & 15) * 4;
        float4 v = *(const float4*)(Kg + ((size_t)(sb + r) * H_DIM + h) * E_DIM + c);
        tile[r][c] = v.x; tile[r][c+1] = v.y; tile[r][c+2] = v.z; tile[r][c+3] = v.w;
    }
    __syncthreads();
    #pragma unroll
    for (int sw = 0; sw < 4; sw++) {            // write coalesced on s
        int e = sw * 16 + (tid >> 4);
        int j = (tid & 15) * 4;
        float4 v = { tile[j][e], tile[j+1][e], tile[j+2][e], tile[j+3][e] };
        *(float4*)(KT + ((size_t)h * E_DIM + e) * S_DIM + sb + j) = v;
    }
}

// ---- kernel 2: fused GEMM + exact top-32 + softmax + V ----
__global__ __launch_bounds__(512, 2)
void topk_attn_kernel(const float* __restrict__ Qg,
                      const float* __restrict__ KT,
                      const float* __restrict__ Vg,
                      float* __restrict__ Out) {
    __shared__ __align__(16) float sS[TT][S_DIM];   // 64 KB scores
    __shared__ unsigned candU[NWAVE][64];
    __shared__ int      candI[NWAVE][64];
    __shared__ unsigned wcnt[NWAVE];

    const int tid  = threadIdx.x;
    const int lane = tid & 63;
    const int wv   = tid >> 6;                 // wave 0..7
    const int bx   = blockIdx.x;
    const int h    = bx & (H_DIM - 1);         // same-h blocks -> same XCD
    const int tb   = bx >> 4;
    const int t0   = tb * TT;                  // block's first t row

    // ---- GEMM: acc[t] = float4 over this wave's 4 consecutive s ----
    float4 acc[TT];
    #pragma unroll
    for (int t = 0; t < TT; t++) acc[t] = make_float4(0.f, 0.f, 0.f, 0.f);

    const int   sb  = wv * 256 + (lane << 2);  // first s of this lane
    const float* kp = KT + (size_t)h * E_DIM * S_DIM + sb;
    const float* Qb = Qg + ((size_t)t0 * H_DIM + h) * E_DIM;  // row stride 1024

    float4 k0 = *(const float4*)(kp);
    float4 k1 = *(const float4*)(kp + S_DIM);
    for (int e2 = 0; e2 < 32; e2++) {
        const int ep = (e2 + 1) & 31;          // wraps to 0 on last iter (harmless)
        float4 n0 = *(const float4*)(kp + (size_t)(2 * ep)     * S_DIM);
        float4 n1 = *(const float4*)(kp + (size_t)(2 * ep + 1) * S_DIM);
        #pragma unroll
        for (int t = 0; t < TT; t++) {
            // uniform address (blockIdx/loop-derived only) -> scalar load
            float2 qv = *(const float2*)(Qb + (size_t)t * (H_DIM * E_DIM) + 2 * e2);
            acc[t].x = fmaf(qv.x, k0.x, acc[t].x);
            acc[t].y = fmaf(qv.x, k0.y, acc[t].y);
            acc[t].z = fmaf(qv.x, k0.z, acc[t].z);
            acc[t].w = fmaf(qv.x, k0.w, acc[t].w);
            acc[t].x = fmaf(qv.y, k1.x, acc[t].x);
            acc[t].y = fmaf(qv.y, k1.y, acc[t].y);
            acc[t].z = fmaf(qv.y, k1.z, acc[t].z);
            acc[t].w = fmaf(qv.y, k1.w, acc[t].w);
        }
        k0 = n0; k1 = n1;
    }

    // ---- LDS transpose: waves<->rows; then selection is wave-local ----
    #pragma unroll
    for (int r = 0; r < TT; r++)
        *(float4*)(&sS[r][sb]) = acc[r];
    __syncthreads();

    // wave wv owns row wv: 32 vals/lane, s = i*64+lane (2-way = free)
    unsigned u[32];
    #pragma unroll
    for (int i = 0; i < 32; i++) u[i] = f2ord(sS[wv][i * 64 + lane]);

    // --- threshold: one fixed-probe count, rare exact bisection fallback ---
    auto wave_count = [&](unsigned t) -> int {   // wave-uniform result
        int c = 0;
        #pragma unroll
        for (int i = 0; i < 32; i++)
            c += __popcll(__ballot(u[i] >= t));
        return c;
    };

    unsigned thr = 0xC1800000u;                // f2ord(16.0f) = 2sigma pre-scale
    int c = wave_count(thr);
    if (c < K_TOP || c > 64) {                 // ~2% of rows
        // invariant: f(lo) >= 32 (f(0)=2048), f(hi) < 32 (f(UINT_MAX)~0)
        unsigned lo = (c >= K_TOP) ? thr : 0u;
        unsigned hi = (c >= K_TOP) ? 0xFFFFFFFFu : thr;
        bool found = false;
        while (!found && (hi - lo > 1u)) {
            unsigned mid = lo + ((hi - lo) >> 1);
            int cm = wave_count(mid);
            if (cm >= K_TOP && cm <= 64) { thr = mid; c = cm; found = true; }
            else if (cm >= K_TOP) lo = mid;
            else hi = mid;
        }
        if (!found) { thr = lo; c = wave_count(lo); }  // exact v32 (dupes clamp)
    }
    int n = (c > 64) ? 64 : c;                 // pathological-duplicate clamp

    // --- collect candidates with u >= thr (tiny per-wave atomic append) ---
    if (lane == 0) wcnt[wv] = 0u;
    #pragma unroll
    for (int i = 0; i < 32; i++) {
        if (u[i] >= thr) {
            unsigned pos = atomicAdd(&wcnt[wv], 1u);
            if (pos < 64u) {
                candU[wv][pos] = u[i];
                candI[wv][pos] = i * 64 + lane;
            }
        }
    }

    // --- 64-wide bitonic, descending by (value, then lower index) ---
    unsigned long long key = 0ull;
    if (lane < n)
        key = (((unsigned long long)candU[wv][lane]) << 32)
            | (unsigned)(~candI[wv][lane]);
    #pragma unroll
    for (int k = 2; k <= 64; k <<= 1)
        #pragma unroll
        for (int j = k >> 1; j > 0; j >>= 1) {
            unsigned long long ok = __shfl_xor(key, j);
            bool takemax = ((lane & j) == 0) ^ ((lane & k) != 0);
            bool mineG   = key > ok;
            key = (takemax == mineG) ? key : ok;
        }

    // --- decode (apply exact pow2 scale now), softmax, V gather, store ---
    const float* Vb = Vg + (size_t)h * E_DIM;
    float val  = ord2f((unsigned)(key >> 32)) * 0.125f;
    int   sidx = (int)(~(unsigned)key);
    float m = __shfl(val, 0);                  // lane 0 = max (n >= 32 always)
    float w = (lane < K_TOP) ? expf(val - m) : 0.f;
    float Z = w;
    #pragma unroll
    for (int d = 32; d > 0; d >>= 1) Z += __shfl_xor(Z, d);
    float pr = w / Z;

    float o = 0.f;
    #pragma unroll
    for (int i2 = 0; i2 < K_TOP; i2++) {
        float pi = __shfl(pr, i2);
        int   s2 = __shfl(sidx, i2);
        o = fmaf(pi, Vb[(size_t)s2 * (H_DIM * E_DIM) + lane], o);
    }
    int t = t0 + wv;
    Out[((size_t)t * H_DIM + h) * E_DIM + lane] = o;
}

extern "C" void kernel_launch(void* const* d_in, const int* in_sizes, int n_in,
                              void* d_out, int out_size, void* d_ws, size_t ws_size,
                              hipStream_t stream) {
    const float* Q = (const float*)d_in[0];
    const float* K = (const float*)d_in[1];
    const float* V = (const float*)d_in[2];
    float* O  = (float*)d_out;
    float* KT = (float*)d_ws;                  // 16*64*2048*4 = 8 MB
    (void)in_sizes; (void)n_in; (void)out_size; (void)ws_size;
    transpose_k<<<dim3(H_DIM * (S_DIM / 64)), dim3(256), 0, stream>>>(K, KT);
    topk_attn_kernel<<<dim3((T_DIM / TT) * H_DIM), dim3(512), 0, stream>>>(Q, KT, V, O);
}